// Round 3
// baseline (217.771 us; speedup 1.0000x reference)
//
#include <hip/hip_runtime.h>
#include <hip/hip_cooperative_groups.h>

namespace cg = cooperative_groups;

#define DDIM 128
#define MSUB 8
#define KCODE 256
#define DSUB 16
#define NLIST 1024
#define NPROBE 32
#define TOPK 100
#define HBINS 4096
#define COLL_CAP 2048
#define RCAP 10

// ==== FROZEN ARITHMETIC (bit-exact vs reference — do not modify) ====

__device__ __forceinline__ float xla_sumsq128(const float* x) {
  float s[16];
  #pragma unroll
  for (int j = 0; j < 16; ++j) {
    float p0 = __fmul_rn(x[j],       x[j]);
    float p1 = __fmul_rn(x[j + 16],  x[j + 16]);
    float p2 = __fmul_rn(x[j + 32],  x[j + 32]);
    float p3 = __fmul_rn(x[j + 48],  x[j + 48]);
    float p4 = __fmul_rn(x[j + 64],  x[j + 64]);
    float p5 = __fmul_rn(x[j + 80],  x[j + 80]);
    float p6 = __fmul_rn(x[j + 96],  x[j + 96]);
    float p7 = __fmul_rn(x[j + 112], x[j + 112]);
    float r0 = __fadd_rn(p0, p4);
    float r1 = __fadd_rn(p1, p5);
    float r2 = __fadd_rn(p2, p6);
    float r3 = __fadd_rn(p3, p7);
    s[j] = __fadd_rn(__fadd_rn(r0, r1), __fadd_rn(r2, r3));
  }
  float a[8], b[4], c[2];
  #pragma unroll
  for (int j = 0; j < 8; ++j) a[j] = __fadd_rn(s[j], s[j + 8]);
  #pragma unroll
  for (int j = 0; j < 4; ++j) b[j] = __fadd_rn(a[j], a[j + 4]);
  #pragma unroll
  for (int j = 0; j < 2; ++j) c[j] = __fadd_rn(b[j], b[j + 2]);
  return __fadd_rn(c[0], c[1]);
}

__device__ __forceinline__ float xla_sumsq16(const float* x) {
  float p[16];
  #pragma unroll
  for (int j = 0; j < 16; ++j) p[j] = __fmul_rn(x[j], x[j]);
  float s8[8], s4[4], s2[2];
  #pragma unroll
  for (int j = 0; j < 8; ++j) s8[j] = __fadd_rn(p[j], p[j + 8]);
  #pragma unroll
  for (int j = 0; j < 4; ++j) s4[j] = __fadd_rn(s8[j], s8[j + 4]);
  #pragma unroll
  for (int j = 0; j < 2; ++j) s2[j] = __fadd_rn(s4[j], s4[j + 2]);
  return __fadd_rn(s2[0], s2[1]);
}

__device__ __forceinline__ float chain_dot16(const float* a, const float* b) {
  float dot = 0.f;
  #pragma unroll
  for (int d = 0; d < DSUB; ++d) dot = __fmaf_rn(a[d], b[d], dot);
  return dot;
}

__device__ __forceinline__ float adc_dist(const float* lut, unsigned long long code) {
  float d = lut[(unsigned)(code & 255ULL)];
  d = __fadd_rn(d, lut[256  + (unsigned)((code >> 8)  & 255ULL)]);
  d = __fadd_rn(d, lut[512  + (unsigned)((code >> 16) & 255ULL)]);
  d = __fadd_rn(d, lut[768  + (unsigned)((code >> 24) & 255ULL)]);
  d = __fadd_rn(d, lut[1024 + (unsigned)((code >> 32) & 255ULL)]);
  d = __fadd_rn(d, lut[1280 + (unsigned)((code >> 40) & 255ULL)]);
  d = __fadd_rn(d, lut[1536 + (unsigned)((code >> 48) & 255ULL)]);
  d = __fadd_rn(d, lut[1792 + (unsigned)((code >> 56) & 255ULL)]);
  return d;
}

// ==== helpers ====
__device__ __forceinline__ unsigned block_scan_incl(unsigned v, volatile unsigned* wsum,
                                                    int t, int nwaves) {
  int lane = t & 63, wid = t >> 6;
  #pragma unroll
  for (int off = 1; off < 64; off <<= 1) {
    unsigned u = __shfl_up(v, off, 64);
    if (lane >= off) v += u;
  }
  if (lane == 63) wsum[wid] = v;
  __syncthreads();
  if (wid == 0 && lane < nwaves) {
    unsigned wv = wsum[lane];
    #pragma unroll
    for (int off = 1; off < 16; off <<= 1) {
      unsigned u = __shfl_up(wv, off, 64);
      if (lane >= off) wv += u;
    }
    wsum[lane] = wv;
  }
  __syncthreads();
  return v + (wid > 0 ? wsum[wid - 1] : 0u);
}

// ---------------- coarse distances only: Q*4 blocks x 256 threads ----------------
// Separate kernel: cbuf[128] needs ~200 VGPRs; a 1024-thread block caps at 128.
__global__ __launch_bounds__(256) void k_coarse(const float* __restrict__ queries,
                                                const float* __restrict__ centroids,
                                                unsigned long long* __restrict__ keys_g) {
  const int qi = blockIdx.x >> 2;
  const int part = blockIdx.x & 3;
  const int t = threadIdx.x;
  __shared__ float qs[DDIM];
  if (t < DDIM) qs[t] = queries[qi * DDIM + t];
  __syncthreads();
  const float qq = xla_sumsq128(qs);
  const int c = part * 256 + t;
  const float* cr = centroids + (size_t)c * DDIM;
  float cbuf[DDIM];
  #pragma unroll
  for (int d = 0; d < DDIM; d += 4) {
    float4 cv = *(const float4*)(cr + d);
    cbuf[d] = cv.x; cbuf[d + 1] = cv.y; cbuf[d + 2] = cv.z; cbuf[d + 3] = cv.w;
  }
  const float cc = xla_sumsq128(cbuf);
  float dot = 0.f;
  #pragma unroll
  for (int d = 0; d < DDIM; ++d) dot = __fmaf_rn(qs[d], cbuf[d], dot);
  float dist = __fsub_rn(__fadd_rn(qq, cc), __fmul_rn(2.0f, dot));
  unsigned bits = __float_as_uint(dist);
  keys_g[(size_t)qi * NLIST + c] = ((unsigned long long)bits << 32) | (unsigned)c;
}

// ---------------- cooperative: hist + scatter + search, Q blocks x 1024 thr ----------
__global__ __launch_bounds__(1024) void k_main(const float* __restrict__ queries,
                                               const float* __restrict__ codebooks,
                                               const int* __restrict__ db_list,
                                               const int* __restrict__ db_codes,
                                               int N,
                                               const unsigned long long* __restrict__ keys_g,
                                               unsigned* __restrict__ counts,
                                               unsigned* __restrict__ cursor,
                                               int4* __restrict__ pack,
                                               int* __restrict__ out) {
  const int qi = blockIdx.x;
  const int t  = threadIdx.x;
  const int NB = gridDim.x;

  __shared__ float qs[DDIM];
  __shared__ float lut_s[MSUB * KCODE];
  __shared__ unsigned hist[HBINS];
  __shared__ unsigned long long coll[COLL_CAP];
  __shared__ unsigned bst[NLIST + 1];
  __shared__ unsigned lhist[NLIST];
  __shared__ unsigned lbase[NLIST];
  __shared__ unsigned pstart[NPROBE], pcum[NPROBE + 1];
  __shared__ unsigned wsum[16];
  __shared__ unsigned scnt;
  __shared__ int sT;

  cg::grid_group grid = cg::this_grid();

  // ---- P0: zero global counters (block 0), block-local db_list hist, LUT ----
  if (t < DDIM) qs[t] = queries[qi * DDIM + t];
  for (int i = t; i < HBINS; i += 1024) hist[i] = 0;
  lhist[t] = 0;                           // blockDim == NLIST == 1024
  if (t == 0) { scnt = 0; sT = HBINS - 1; }
  if (qi == 0) { counts[t] = 0; cursor[t] = 0; }
  __syncthreads();

  const int CPB = (N + NB * 1024 - 1) / (NB * 1024);   // 1024-elem chunks per block
  #pragma unroll 1
  for (int k = 0; k < CPB; ++k) {
    int n = (qi * CPB + k) * 1024 + t;
    if (n < N) atomicAdd(&lhist[db_list[n]], 1u);
  }

  // LUT (frozen arithmetic), 2 entries per thread
  #pragma unroll
  for (int j = 0; j < (MSUB * KCODE) / 1024; ++j) {
    int idx = j * 1024 + t;
    const float* cb = codebooks + (size_t)idx * DSUB;
    const float* qsub = qs + (idx >> 8) * DSUB;  // KCODE == 256
    float cbv[DSUB], qv[DSUB];
    #pragma unroll
    for (int d = 0; d < DSUB; ++d) { cbv[d] = cb[d]; qv[d] = qsub[d]; }
    const float qq16 = xla_sumsq16(qv);
    const float cc16 = xla_sumsq16(cbv);
    const float dot16 = chain_dot16(qv, cbv);
    lut_s[idx] = __fsub_rn(__fadd_rn(qq16, cc16), __fmul_rn(2.0f, dot16));
  }

  grid.sync();   // counts/cursor zeroed everywhere

  // ---- P1: merge local hist into global counts ----
  { unsigned c = lhist[t]; if (c) atomicAdd(&counts[t], c); }

  grid.sync();   // counts final

  // ---- P2: bucket offsets + scatter (reuses lhist from P0) ----
  {
    unsigned v = counts[t];
    unsigned incl = block_scan_incl(v, wsum, t, 16);
    bst[t + 1] = incl;
    if (t == 0) bst[0] = 0;
  }
  __syncthreads();
  {
    unsigned cnt = lhist[t];
    if (cnt) lbase[t] = bst[t] + atomicAdd(&cursor[t], cnt);
    lhist[t] = 0;
  }
  __syncthreads();
  #pragma unroll 1
  for (int k = 0; k < CPB; ++k) {
    int n = (qi * CPB + k) * 1024 + t;
    if (n < N) {
      int l = db_list[n];
      unsigned pos = lbase[l] + atomicAdd(&lhist[l], 1u);
      const int4* cp = (const int4*)(db_codes + (size_t)n * MSUB);
      int4 c0 = cp[0], c1 = cp[1];
      unsigned lo = (unsigned)(c0.x & 255) | ((unsigned)(c0.y & 255) << 8) |
                    ((unsigned)(c0.z & 255) << 16) | ((unsigned)(c0.w & 255) << 24);
      unsigned hi = (unsigned)(c1.x & 255) | ((unsigned)(c1.y & 255) << 8) |
                    ((unsigned)(c1.z & 255) << 16) | ((unsigned)(c1.w & 255) << 24);
      pack[pos] = make_int4((int)lo, (int)hi, n, 0);
    }
  }

  grid.sync();   // pack complete device-wide

  // ---- P3: per-query search (identical logic to previous k_search) ----
  const unsigned long long ckey = keys_g[(size_t)qi * NLIST + t];

  // coarse top-NPROBE selection
  atomicAdd(&hist[(unsigned)(ckey >> 51)], 1u);
  __syncthreads();
  {
    unsigned mysum = 0;
    #pragma unroll
    for (int i = 0; i < 4; ++i) mysum += hist[t * 4 + i];
    unsigned incl = block_scan_incl(mysum, wsum, t, 16);
    unsigned excl = incl - mysum;
    if (excl < NPROBE && NPROBE <= incl) {
      unsigned c2 = excl;
      #pragma unroll
      for (int i = 0; i < 4; ++i) {
        unsigned h = hist[t * 4 + i];
        if (c2 + h >= NPROBE) { sT = t * 4 + i; break; }
        c2 += h;
      }
    }
  }
  __syncthreads();
  {
    const int T32 = sT;
    if ((int)(ckey >> 51) <= T32) {
      unsigned p = atomicAdd(&scnt, 1u);
      if (p < 512) coll[p] = ckey;
    }
  }
  __syncthreads();
  {
    unsigned cnt = scnt; if (cnt > 512) cnt = 512;
    for (unsigned i = t; i < cnt; i += 1024) {
      unsigned long long k2 = coll[i];
      unsigned r = 0;
      for (unsigned j = 0; j < cnt; ++j) r += (coll[j] < k2) ? 1u : 0u;
      if (r < NPROBE) {
        unsigned l = (unsigned)(k2 & 0xffffffffULL);
        pstart[r] = bst[l];
        pcum[r + 1] = bst[l + 1] - bst[l];
      }
    }
  }
  __syncthreads();
  // reset for ADC phase
  for (int i = t; i < HBINS; i += 1024) hist[i] = 0;
  if (t == 0) {
    scnt = 0; sT = HBINS - 1;
    unsigned acc = 0;
    pcum[0] = 0;
    for (int j = 1; j <= NPROBE; ++j) { acc += pcum[j]; pcum[j] = acc; }
  }
  __syncthreads();
  const unsigned total = pcum[NPROBE];

  // pass 1: ADC once, keys in STATICALLY-indexed registers, monotonic probe walk
  unsigned long long regkey[RCAP];
  int lo = 0;
  #pragma unroll
  for (int s = 0; s < RCAP; ++s) {
    unsigned g = (unsigned)t + (unsigned)(s * 1024);
    if (g < total) {
      while (pcum[lo + 1] <= g) ++lo;
      unsigned addr = pstart[lo] + (g - pcum[lo]);
      int4 w = pack[addr];
      unsigned long long code = (unsigned)w.x | ((unsigned long long)(unsigned)w.y << 32);
      unsigned bits = __float_as_uint(adc_dist(lut_s, code));
      regkey[s] = ((unsigned long long)bits << 32) | (unsigned)w.z;
      atomicAdd(&hist[bits >> 19], 1u);
    }
  }
  // defensive tail (never taken at this problem size: RCAP*1024 = 10240 > max total)
  for (unsigned g = (unsigned)t + RCAP * 1024; g < total; g += 1024) {
    while (pcum[lo + 1] <= g) ++lo;
    unsigned addr = pstart[lo] + (g - pcum[lo]);
    int4 w = pack[addr];
    unsigned long long code = (unsigned)w.x | ((unsigned long long)(unsigned)w.y << 32);
    unsigned bits = __float_as_uint(adc_dist(lut_s, code));
    atomicAdd(&hist[bits >> 19], 1u);
  }
  __syncthreads();

  // find T = bin containing rank TOPK
  {
    unsigned mysum = 0;
    #pragma unroll
    for (int i = 0; i < 4; ++i) mysum += hist[t * 4 + i];
    unsigned incl = block_scan_incl(mysum, wsum, t, 16);
    unsigned excl = incl - mysum;
    if (excl < TOPK && TOPK <= incl) {
      unsigned c = excl;
      #pragma unroll
      for (int i = 0; i < 4; ++i) {
        unsigned h = hist[t * 4 + i];
        if (c + h >= TOPK) { sT = t * 4 + i; break; }
        c += h;
      }
    }
  }
  __syncthreads();
  const int T = sT;

  // pass 2: collect ALL candidates with bin <= T (register replay)
  {
    #pragma unroll
    for (int s = 0; s < RCAP; ++s) {
      unsigned g = (unsigned)t + (unsigned)(s * 1024);
      if (g < total) {
        unsigned long long k2 = regkey[s];
        if ((int)(unsigned)(k2 >> 51) <= T) {   // == bits >> 19
          unsigned p = atomicAdd(&scnt, 1u);
          if (p < COLL_CAP) coll[p] = k2;
        }
      }
    }
    int lo2 = 0;
    for (unsigned g = (unsigned)t + RCAP * 1024; g < total; g += 1024) {
      while (pcum[lo2 + 1] <= g) ++lo2;
      unsigned addr = pstart[lo2] + (g - pcum[lo2]);
      int4 w = pack[addr];
      unsigned long long code = (unsigned)w.x | ((unsigned long long)(unsigned)w.y << 32);
      unsigned bits = __float_as_uint(adc_dist(lut_s, code));
      if ((int)(bits >> 19) <= T) {
        unsigned p = atomicAdd(&scnt, 1u);
        if (p < COLL_CAP) coll[p] = ((unsigned long long)bits << 32) | (unsigned)w.z;
      }
    }
  }
  __syncthreads();

  // exact rank by (fp32 bits, index)
  unsigned cnt = scnt;
  if (cnt > COLL_CAP) cnt = COLL_CAP;
  for (unsigned i = t; i < cnt; i += 1024) {
    unsigned long long key = coll[i];
    unsigned r = 0;
    for (unsigned j = 0; j < cnt; ++j) r += (coll[j] < key) ? 1u : 0u;
    if (r < TOPK) out[qi * TOPK + r] = (int)(key & 0xffffffffULL);
  }
}

extern "C" void kernel_launch(void* const* d_in, const int* in_sizes, int n_in,
                              void* d_out, int out_size, void* d_ws, size_t ws_size,
                              hipStream_t stream) {
  const float* queries   = (const float*)d_in[0];
  const float* centroids = (const float*)d_in[1];
  const float* codebooks = (const float*)d_in[2];
  const int*   db_codes  = (const int*)d_in[3];
  const int*   db_list   = (const int*)d_in[4];
  int N = in_sizes[4];
  const int Q = in_sizes[0] / DDIM;
  int* out = (int*)d_out;

  char* p = (char*)d_ws;
  unsigned long long* keys_g = (unsigned long long*)p; p += (size_t)Q * NLIST * 8;
  unsigned* counts = (unsigned*)p;                  p += NLIST * 4;
  unsigned* cursor = (unsigned*)p;                  p += NLIST * 4;
  int4* pack = (int4*)p;                            p += (size_t)N * 16;

  k_coarse<<<Q * 4, 256, 0, stream>>>(queries, centroids, keys_g);

  void* kargs[] = {(void*)&queries, (void*)&codebooks, (void*)&db_list,
                   (void*)&db_codes, (void*)&N, (void*)&keys_g,
                   (void*)&counts, (void*)&cursor, (void*)&pack, (void*)&out};
  hipLaunchCooperativeKernel((void*)k_main, dim3(Q), dim3(1024), kargs, 0, stream);
}

// Round 4
// 167.170 us; speedup vs baseline: 1.3027x; 1.3027x over previous
//
#include <hip/hip_runtime.h>

#define DDIM 128
#define MSUB 8
#define KCODE 256
#define DSUB 16
#define NLIST 1024
#define NPROBE 32
#define TOPK 100
#define HBINS 4096
#define COLL_CAP 2048
#define RCAP 10
#define SCHUNK 512

// ==== FROZEN ARITHMETIC (bit-exact vs reference — do not modify) ====

__device__ __forceinline__ float xla_sumsq128(const float* x) {
  float s[16];
  #pragma unroll
  for (int j = 0; j < 16; ++j) {
    float p0 = __fmul_rn(x[j],       x[j]);
    float p1 = __fmul_rn(x[j + 16],  x[j + 16]);
    float p2 = __fmul_rn(x[j + 32],  x[j + 32]);
    float p3 = __fmul_rn(x[j + 48],  x[j + 48]);
    float p4 = __fmul_rn(x[j + 64],  x[j + 64]);
    float p5 = __fmul_rn(x[j + 80],  x[j + 80]);
    float p6 = __fmul_rn(x[j + 96],  x[j + 96]);
    float p7 = __fmul_rn(x[j + 112], x[j + 112]);
    float r0 = __fadd_rn(p0, p4);
    float r1 = __fadd_rn(p1, p5);
    float r2 = __fadd_rn(p2, p6);
    float r3 = __fadd_rn(p3, p7);
    s[j] = __fadd_rn(__fadd_rn(r0, r1), __fadd_rn(r2, r3));
  }
  float a[8], b[4], c[2];
  #pragma unroll
  for (int j = 0; j < 8; ++j) a[j] = __fadd_rn(s[j], s[j + 8]);
  #pragma unroll
  for (int j = 0; j < 4; ++j) b[j] = __fadd_rn(a[j], a[j + 4]);
  #pragma unroll
  for (int j = 0; j < 2; ++j) c[j] = __fadd_rn(b[j], b[j + 2]);
  return __fadd_rn(c[0], c[1]);
}

__device__ __forceinline__ float xla_sumsq16(const float* x) {
  float p[16];
  #pragma unroll
  for (int j = 0; j < 16; ++j) p[j] = __fmul_rn(x[j], x[j]);
  float s8[8], s4[4], s2[2];
  #pragma unroll
  for (int j = 0; j < 8; ++j) s8[j] = __fadd_rn(p[j], p[j + 8]);
  #pragma unroll
  for (int j = 0; j < 4; ++j) s4[j] = __fadd_rn(s8[j], s8[j + 4]);
  #pragma unroll
  for (int j = 0; j < 2; ++j) s2[j] = __fadd_rn(s4[j], s4[j + 2]);
  return __fadd_rn(s2[0], s2[1]);
}

__device__ __forceinline__ float chain_dot16(const float* a, const float* b) {
  float dot = 0.f;
  #pragma unroll
  for (int d = 0; d < DSUB; ++d) dot = __fmaf_rn(a[d], b[d], dot);
  return dot;
}

__device__ __forceinline__ float adc_dist(const float* lut, unsigned long long code) {
  float d = lut[(unsigned)(code & 255ULL)];
  d = __fadd_rn(d, lut[256  + (unsigned)((code >> 8)  & 255ULL)]);
  d = __fadd_rn(d, lut[512  + (unsigned)((code >> 16) & 255ULL)]);
  d = __fadd_rn(d, lut[768  + (unsigned)((code >> 24) & 255ULL)]);
  d = __fadd_rn(d, lut[1024 + (unsigned)((code >> 32) & 255ULL)]);
  d = __fadd_rn(d, lut[1280 + (unsigned)((code >> 40) & 255ULL)]);
  d = __fadd_rn(d, lut[1536 + (unsigned)((code >> 48) & 255ULL)]);
  d = __fadd_rn(d, lut[1792 + (unsigned)((code >> 56) & 255ULL)]);
  return d;
}

// ==== helpers ====
__device__ __forceinline__ unsigned block_scan_incl(unsigned v, volatile unsigned* wsum,
                                                    int t, int nwaves) {
  int lane = t & 63, wid = t >> 6;
  #pragma unroll
  for (int off = 1; off < 64; off <<= 1) {
    unsigned u = __shfl_up(v, off, 64);
    if (lane >= off) v += u;
  }
  if (lane == 63) wsum[wid] = v;
  __syncthreads();
  if (wid == 0 && lane < nwaves) {
    unsigned wv = wsum[lane];
    #pragma unroll
    for (int off = 1; off < 16; off <<= 1) {
      unsigned u = __shfl_up(wv, off, 64);
      if (lane >= off) wv += u;
    }
    wsum[lane] = wv;
  }
  __syncthreads();
  return v + (wid > 0 ? wsum[wid - 1] : 0u);
}

// ------- coarse distances + fused db_list histogram: Q*4 blocks x 256 threads -------
// Separate kernel: cbuf[128] needs ~200 VGPRs; 256-thread blocks get their own budget.
// Histogram atomics issue early and hide under the coarse FMA storm.
__global__ __launch_bounds__(256) void k_coarse(const float* __restrict__ queries,
                                                const float* __restrict__ centroids,
                                                const int* __restrict__ db_list, int N,
                                                unsigned long long* __restrict__ keys_g,
                                                unsigned* __restrict__ counts) {
  const int qi = blockIdx.x >> 2;
  const int part = blockIdx.x & 3;
  const int t = threadIdx.x;
  __shared__ float qs[DDIM];
  if (t < DDIM) qs[t] = queries[qi * DDIM + t];

  // fused histogram slice: contiguous CH-range per block, 1 global atomic per element
  {
    const int G = (int)gridDim.x;
    const int CH = (N + G - 1) / G;
    const int b0 = blockIdx.x * CH;
    for (int i = t; i < CH; i += 256) {
      int n = b0 + i;
      if (n < N) atomicAdd(&counts[db_list[n]], 1u);
    }
  }
  __syncthreads();

  const float qq = xla_sumsq128(qs);
  const int c = part * 256 + t;
  const float* cr = centroids + (size_t)c * DDIM;
  float cbuf[DDIM];
  #pragma unroll
  for (int d = 0; d < DDIM; d += 4) {
    float4 cv = *(const float4*)(cr + d);
    cbuf[d] = cv.x; cbuf[d + 1] = cv.y; cbuf[d + 2] = cv.z; cbuf[d + 3] = cv.w;
  }
  const float cc = xla_sumsq128(cbuf);
  float dot = 0.f;
  #pragma unroll
  for (int d = 0; d < DDIM; ++d) dot = __fmaf_rn(qs[d], cbuf[d], dot);
  float dist = __fsub_rn(__fadd_rn(qq, cc), __fmul_rn(2.0f, dot));
  unsigned bits = __float_as_uint(dist);
  keys_g[(size_t)qi * NLIST + c] = ((unsigned long long)bits << 32) | (unsigned)c;
}

// ---------------- block-aggregated bucket scatter with local scan ----------------
// SCHUNK=512 -> ~489 blocks -> 2 blocks/CU (8 waves) for latency hiding.
__global__ __launch_bounds__(256) void k_scatter(const int* __restrict__ db_list,
                                                 const int* __restrict__ db_codes, int N,
                                                 const unsigned* __restrict__ counts,
                                                 unsigned* __restrict__ cursor,
                                                 int4* __restrict__ pack) {
  __shared__ unsigned lhist[NLIST], lbase[NLIST], sbstart[NLIST];
  __shared__ unsigned wsum[16];
  const int t = threadIdx.x;
  const int base = blockIdx.x * SCHUNK;
  {
    unsigned c0 = counts[t * 4], c1 = counts[t * 4 + 1],
             c2 = counts[t * 4 + 2], c3 = counts[t * 4 + 3];
    unsigned sum4 = c0 + c1 + c2 + c3;
    unsigned incl = block_scan_incl(sum4, wsum, t, 4);
    unsigned excl = incl - sum4;
    sbstart[t * 4] = excl;
    sbstart[t * 4 + 1] = excl + c0;
    sbstart[t * 4 + 2] = excl + c0 + c1;
    sbstart[t * 4 + 3] = excl + c0 + c1 + c2;
  }
  for (int i = t; i < NLIST; i += 256) lhist[i] = 0;
  __syncthreads();
  #pragma unroll
  for (int k = 0; k < SCHUNK / 256; ++k) {
    int n = base + k * 256 + t;
    if (n < N) atomicAdd(&lhist[db_list[n]], 1u);
  }
  __syncthreads();
  for (int i = t; i < NLIST; i += 256) {
    unsigned cnt = lhist[i];
    if (cnt) lbase[i] = sbstart[i] + atomicAdd(&cursor[i], cnt);
    lhist[i] = 0;
  }
  __syncthreads();
  #pragma unroll
  for (int k = 0; k < SCHUNK / 256; ++k) {
    int n = base + k * 256 + t;
    if (n < N) {
      int l = db_list[n];
      unsigned pos = lbase[l] + atomicAdd(&lhist[l], 1u);
      const int4* cp = (const int4*)(db_codes + (size_t)n * MSUB);
      int4 c0 = cp[0], c1 = cp[1];
      unsigned lo = (unsigned)(c0.x & 255) | ((unsigned)(c0.y & 255) << 8) |
                    ((unsigned)(c0.z & 255) << 16) | ((unsigned)(c0.w & 255) << 24);
      unsigned hi = (unsigned)(c1.x & 255) | ((unsigned)(c1.y & 255) << 8) |
                    ((unsigned)(c1.z & 255) << 16) | ((unsigned)(c1.w & 255) << 24);
      pack[pos] = make_int4((int)lo, (int)hi, n, 0);
    }
  }
}

// ---------------- search: LUT + coarse select + ADC + top-k, 1024 thr/query ----
__global__ __launch_bounds__(1024, 1) void k_search(const float* __restrict__ queries,
                                                    const float* __restrict__ codebooks,
                                                    const unsigned long long* __restrict__ keys_g,
                                                    const unsigned* __restrict__ counts,
                                                    const int4* __restrict__ pack,
                                                    int* __restrict__ out) {
  const int qi = blockIdx.x;
  const int t = threadIdx.x;
  __shared__ float qs[DDIM];
  __shared__ float lut_s[MSUB * KCODE];
  __shared__ unsigned hist[HBINS];
  __shared__ unsigned long long coll[COLL_CAP];
  __shared__ unsigned bst[NLIST + 1];
  __shared__ unsigned pstart[NPROBE], pcum[NPROBE + 1];
  __shared__ unsigned wsum[16];
  __shared__ unsigned scnt;
  __shared__ int sT;

  if (t < DDIM) qs[t] = queries[qi * DDIM + t];
  const unsigned long long ckey = keys_g[(size_t)qi * NLIST + t];
  for (int i = t; i < HBINS; i += 1024) hist[i] = 0;
  if (t == 0) { scnt = 0; sT = HBINS - 1; }
  // bst = exclusive prefix of counts (internal syncs also cover qs/hist init)
  {
    unsigned v = counts[t];
    unsigned incl = block_scan_incl(v, wsum, t, 16);
    bst[t + 1] = incl;
    if (t == 0) bst[0] = 0;
  }
  __syncthreads();

  // ---- LUT (frozen arithmetic), 2 entries per thread ----
  #pragma unroll
  for (int j = 0; j < (MSUB * KCODE) / 1024; ++j) {
    int idx = j * 1024 + t;
    const float* cb = codebooks + (size_t)idx * DSUB;
    const float* qsub = qs + (idx >> 8) * DSUB;  // KCODE == 256
    float cbv[DSUB], qv[DSUB];
    #pragma unroll
    for (int d = 0; d < DSUB; ++d) { cbv[d] = cb[d]; qv[d] = qsub[d]; }
    const float qq16 = xla_sumsq16(qv);
    const float cc16 = xla_sumsq16(cbv);
    const float dot16 = chain_dot16(qv, cbv);
    lut_s[idx] = __fsub_rn(__fadd_rn(qq16, cc16), __fmul_rn(2.0f, dot16));
  }

  // ---- coarse top-NPROBE selection from ckey ----
  atomicAdd(&hist[(unsigned)(ckey >> 51)], 1u);
  __syncthreads();
  {
    unsigned mysum = 0;
    #pragma unroll
    for (int i = 0; i < 4; ++i) mysum += hist[t * 4 + i];
    unsigned incl = block_scan_incl(mysum, wsum, t, 16);
    unsigned excl = incl - mysum;
    if (excl < NPROBE && NPROBE <= incl) {
      unsigned c2 = excl;
      #pragma unroll
      for (int i = 0; i < 4; ++i) {
        unsigned h = hist[t * 4 + i];
        if (c2 + h >= NPROBE) { sT = t * 4 + i; break; }
        c2 += h;
      }
    }
  }
  __syncthreads();
  {
    const int T32 = sT;
    if ((int)(ckey >> 51) <= T32) {
      unsigned p = atomicAdd(&scnt, 1u);
      if (p < 512) coll[p] = ckey;
    }
  }
  __syncthreads();
  {
    unsigned cnt = scnt; if (cnt > 512) cnt = 512;
    for (unsigned i = t; i < cnt; i += 1024) {
      unsigned long long k2 = coll[i];
      unsigned r = 0;
      for (unsigned j = 0; j < cnt; ++j) r += (coll[j] < k2) ? 1u : 0u;
      if (r < NPROBE) {
        unsigned l = (unsigned)(k2 & 0xffffffffULL);
        pstart[r] = bst[l];
        pcum[r + 1] = bst[l + 1] - bst[l];
      }
    }
  }
  __syncthreads();
  // reset for ADC phase
  for (int i = t; i < HBINS; i += 1024) hist[i] = 0;
  if (t == 0) {
    scnt = 0; sT = HBINS - 1;
    unsigned acc = 0;
    pcum[0] = 0;
    for (int j = 1; j <= NPROBE; ++j) { acc += pcum[j]; pcum[j] = acc; }
  }
  __syncthreads();
  const unsigned total = pcum[NPROBE];

  // ---- pass 1: ADC once, keys in STATICALLY-indexed registers,
  //      probe lookup via monotonic walk (g strictly increases per thread) ----
  unsigned long long regkey[RCAP];
  int lo = 0;
  #pragma unroll
  for (int s = 0; s < RCAP; ++s) {
    unsigned g = (unsigned)t + (unsigned)(s * 1024);
    if (g < total) {
      while (pcum[lo + 1] <= g) ++lo;
      unsigned addr = pstart[lo] + (g - pcum[lo]);
      int4 w = pack[addr];
      unsigned long long code = (unsigned)w.x | ((unsigned long long)(unsigned)w.y << 32);
      unsigned bits = __float_as_uint(adc_dist(lut_s, code));
      regkey[s] = ((unsigned long long)bits << 32) | (unsigned)w.z;
      atomicAdd(&hist[bits >> 19], 1u);
    }
  }
  // defensive tail (never taken at this problem size: RCAP*1024 = 10240 > max total)
  for (unsigned g = (unsigned)t + RCAP * 1024; g < total; g += 1024) {
    while (pcum[lo + 1] <= g) ++lo;
    unsigned addr = pstart[lo] + (g - pcum[lo]);
    int4 w = pack[addr];
    unsigned long long code = (unsigned)w.x | ((unsigned long long)(unsigned)w.y << 32);
    unsigned bits = __float_as_uint(adc_dist(lut_s, code));
    atomicAdd(&hist[bits >> 19], 1u);
  }
  __syncthreads();

  // ---- find T = bin containing rank TOPK ----
  {
    unsigned mysum = 0;
    #pragma unroll
    for (int i = 0; i < 4; ++i) mysum += hist[t * 4 + i];
    unsigned incl = block_scan_incl(mysum, wsum, t, 16);
    unsigned excl = incl - mysum;
    if (excl < TOPK && TOPK <= incl) {
      unsigned c = excl;
      #pragma unroll
      for (int i = 0; i < 4; ++i) {
        unsigned h = hist[t * 4 + i];
        if (c + h >= TOPK) { sT = t * 4 + i; break; }
        c += h;
      }
    }
  }
  __syncthreads();
  const int T = sT;

  // ---- pass 2: collect ALL candidates with bin <= T (register replay) ----
  {
    #pragma unroll
    for (int s = 0; s < RCAP; ++s) {
      unsigned g = (unsigned)t + (unsigned)(s * 1024);
      if (g < total) {
        unsigned long long k2 = regkey[s];
        if ((int)(unsigned)(k2 >> 51) <= T) {   // == bits >> 19
          unsigned p = atomicAdd(&scnt, 1u);
          if (p < COLL_CAP) coll[p] = k2;
        }
      }
    }
    int lo2 = 0;
    for (unsigned g = (unsigned)t + RCAP * 1024; g < total; g += 1024) {
      while (pcum[lo2 + 1] <= g) ++lo2;
      unsigned addr = pstart[lo2] + (g - pcum[lo2]);
      int4 w = pack[addr];
      unsigned long long code = (unsigned)w.x | ((unsigned long long)(unsigned)w.y << 32);
      unsigned bits = __float_as_uint(adc_dist(lut_s, code));
      if ((int)(bits >> 19) <= T) {
        unsigned p = atomicAdd(&scnt, 1u);
        if (p < COLL_CAP) coll[p] = ((unsigned long long)bits << 32) | (unsigned)w.z;
      }
    }
  }
  __syncthreads();

  // ---- exact rank by (fp32 bits, index) ----
  unsigned cnt = scnt;
  if (cnt > COLL_CAP) cnt = COLL_CAP;
  for (unsigned i = t; i < cnt; i += 1024) {
    unsigned long long key = coll[i];
    unsigned r = 0;
    for (unsigned j = 0; j < cnt; ++j) r += (coll[j] < key) ? 1u : 0u;
    if (r < TOPK) out[qi * TOPK + r] = (int)(key & 0xffffffffULL);
  }
}

extern "C" void kernel_launch(void* const* d_in, const int* in_sizes, int n_in,
                              void* d_out, int out_size, void* d_ws, size_t ws_size,
                              hipStream_t stream) {
  const float* queries   = (const float*)d_in[0];
  const float* centroids = (const float*)d_in[1];
  const float* codebooks = (const float*)d_in[2];
  const int*   db_codes  = (const int*)d_in[3];
  const int*   db_list   = (const int*)d_in[4];
  const int N = in_sizes[4];
  const int Q = in_sizes[0] / DDIM;
  int* out = (int*)d_out;

  char* p = (char*)d_ws;
  unsigned long long* keys_g = (unsigned long long*)p; p += (size_t)Q * NLIST * 8;
  unsigned* counts = (unsigned*)p;                  p += NLIST * 4;
  unsigned* cursor = (unsigned*)p;                  p += NLIST * 4;
  int4* pack = (int4*)p;                            p += (size_t)N * 16;

  hipMemsetAsync(counts, 0, (size_t)NLIST * 4 * 2, stream); // counts + cursor

  k_coarse<<<Q * 4, 256, 0, stream>>>(queries, centroids, db_list, N, keys_g, counts);
  k_scatter<<<(N + SCHUNK - 1) / SCHUNK, 256, 0, stream>>>(db_list, db_codes, N,
                                                           counts, cursor, pack);
  k_search<<<Q, 1024, 0, stream>>>(queries, codebooks, keys_g, counts, pack, out);
}

// Round 5
// 126.360 us; speedup vs baseline: 1.7234x; 1.3230x over previous
//
#include <hip/hip_runtime.h>

#define DDIM 128
#define MSUB 8
#define KCODE 256
#define DSUB 16
#define NLIST 1024
#define NPROBE 32
#define TOPK 100
#define HBINS 4096
#define COLL_CAP 2048
#define RCAP 10
#define SCHUNK 1024
#define STHREADS 512

// ==== FROZEN ARITHMETIC (bit-exact vs reference — do not modify) ====

__device__ __forceinline__ float xla_sumsq128(const float* x) {
  float s[16];
  #pragma unroll
  for (int j = 0; j < 16; ++j) {
    float p0 = __fmul_rn(x[j],       x[j]);
    float p1 = __fmul_rn(x[j + 16],  x[j + 16]);
    float p2 = __fmul_rn(x[j + 32],  x[j + 32]);
    float p3 = __fmul_rn(x[j + 48],  x[j + 48]);
    float p4 = __fmul_rn(x[j + 64],  x[j + 64]);
    float p5 = __fmul_rn(x[j + 80],  x[j + 80]);
    float p6 = __fmul_rn(x[j + 96],  x[j + 96]);
    float p7 = __fmul_rn(x[j + 112], x[j + 112]);
    float r0 = __fadd_rn(p0, p4);
    float r1 = __fadd_rn(p1, p5);
    float r2 = __fadd_rn(p2, p6);
    float r3 = __fadd_rn(p3, p7);
    s[j] = __fadd_rn(__fadd_rn(r0, r1), __fadd_rn(r2, r3));
  }
  float a[8], b[4], c[2];
  #pragma unroll
  for (int j = 0; j < 8; ++j) a[j] = __fadd_rn(s[j], s[j + 8]);
  #pragma unroll
  for (int j = 0; j < 4; ++j) b[j] = __fadd_rn(a[j], a[j + 4]);
  #pragma unroll
  for (int j = 0; j < 2; ++j) c[j] = __fadd_rn(b[j], b[j + 2]);
  return __fadd_rn(c[0], c[1]);
}

__device__ __forceinline__ float xla_sumsq16(const float* x) {
  float p[16];
  #pragma unroll
  for (int j = 0; j < 16; ++j) p[j] = __fmul_rn(x[j], x[j]);
  float s8[8], s4[4], s2[2];
  #pragma unroll
  for (int j = 0; j < 8; ++j) s8[j] = __fadd_rn(p[j], p[j + 8]);
  #pragma unroll
  for (int j = 0; j < 4; ++j) s4[j] = __fadd_rn(s8[j], s8[j + 4]);
  #pragma unroll
  for (int j = 0; j < 2; ++j) s2[j] = __fadd_rn(s4[j], s4[j + 2]);
  return __fadd_rn(s2[0], s2[1]);
}

__device__ __forceinline__ float chain_dot16(const float* a, const float* b) {
  float dot = 0.f;
  #pragma unroll
  for (int d = 0; d < DSUB; ++d) dot = __fmaf_rn(a[d], b[d], dot);
  return dot;
}

__device__ __forceinline__ float adc_dist(const float* lut, unsigned long long code) {
  float d = lut[(unsigned)(code & 255ULL)];
  d = __fadd_rn(d, lut[256  + (unsigned)((code >> 8)  & 255ULL)]);
  d = __fadd_rn(d, lut[512  + (unsigned)((code >> 16) & 255ULL)]);
  d = __fadd_rn(d, lut[768  + (unsigned)((code >> 24) & 255ULL)]);
  d = __fadd_rn(d, lut[1024 + (unsigned)((code >> 32) & 255ULL)]);
  d = __fadd_rn(d, lut[1280 + (unsigned)((code >> 40) & 255ULL)]);
  d = __fadd_rn(d, lut[1536 + (unsigned)((code >> 48) & 255ULL)]);
  d = __fadd_rn(d, lut[1792 + (unsigned)((code >> 56) & 255ULL)]);
  return d;
}

// ==== helpers ====
__device__ __forceinline__ unsigned block_scan_incl(unsigned v, volatile unsigned* wsum,
                                                    int t, int nwaves) {
  int lane = t & 63, wid = t >> 6;
  #pragma unroll
  for (int off = 1; off < 64; off <<= 1) {
    unsigned u = __shfl_up(v, off, 64);
    if (lane >= off) v += u;
  }
  if (lane == 63) wsum[wid] = v;
  __syncthreads();
  if (wid == 0 && lane < nwaves) {
    unsigned wv = wsum[lane];
    #pragma unroll
    for (int off = 1; off < 16; off <<= 1) {
      unsigned u = __shfl_up(wv, off, 64);
      if (lane >= off) wv += u;
    }
    wsum[lane] = wv;
  }
  __syncthreads();
  return v + (wid > 0 ? wsum[wid - 1] : 0u);
}

// ------- front: coarse distances (1024 blocks) + LDS-aggregated db_list hist
//         (256 blocks), role-interleaved in one dispatch: grid = 1280 x 256 thr.
//         Roles are independent (different inputs/outputs, no ordering needed);
//         hist blocks are memory-bound and co-schedule under coarse's VALU work.
__global__ __launch_bounds__(256) void k_front(const float* __restrict__ queries,
                                               const float* __restrict__ centroids,
                                               const int* __restrict__ db_list, int N,
                                               unsigned long long* __restrict__ keys_g,
                                               unsigned* __restrict__ counts) {
  const int t = threadIdx.x;
  const int r  = blockIdx.x % 5;
  const int b5 = blockIdx.x / 5;

  if (r == 0) {
    // ---- hist role (exact round-2 k_hist body, bid = b5, 256 blocks) ----
    __shared__ unsigned hist_l[NLIST];
    for (int i = t; i < NLIST; i += 256) hist_l[i] = 0;
    __syncthreads();
    for (int n = b5 * 256 + t; n < N; n += 256 * 256)
      atomicAdd(&hist_l[db_list[n]], 1u);
    __syncthreads();
    for (int i = t; i < NLIST; i += 256)
      if (hist_l[i]) atomicAdd(&counts[i], hist_l[i]);
    return;
  }

  // ---- coarse role (exact round-2 k_coarse body, cid = b5*4 + (r-1)) ----
  const int cid = b5 * 4 + (r - 1);
  const int qi = cid >> 2;
  const int part = cid & 3;
  __shared__ float qs[DDIM];
  if (t < DDIM) qs[t] = queries[qi * DDIM + t];
  __syncthreads();
  const float qq = xla_sumsq128(qs);
  const int c = part * 256 + t;
  const float* cr = centroids + (size_t)c * DDIM;
  float cbuf[DDIM];
  #pragma unroll
  for (int d = 0; d < DDIM; d += 4) {
    float4 cv = *(const float4*)(cr + d);
    cbuf[d] = cv.x; cbuf[d + 1] = cv.y; cbuf[d + 2] = cv.z; cbuf[d + 3] = cv.w;
  }
  const float cc = xla_sumsq128(cbuf);
  float dot = 0.f;
  #pragma unroll
  for (int d = 0; d < DDIM; ++d) dot = __fmaf_rn(qs[d], cbuf[d], dot);
  float dist = __fsub_rn(__fadd_rn(qq, cc), __fmul_rn(2.0f, dot));
  unsigned bits = __float_as_uint(dist);
  keys_g[(size_t)qi * NLIST + c] = ((unsigned long long)bits << 32) | (unsigned)c;
}

// ---------------- block-aggregated bucket scatter with local scan ----------------
// 512 threads, SCHUNK=1024 -> 245 blocks (~1/CU) at 8 waves/CU for latency hiding,
// same chunk size as round 2 (longer per-list segments -> less pack false sharing).
__global__ __launch_bounds__(STHREADS) void k_scatter(const int* __restrict__ db_list,
                                                      const int* __restrict__ db_codes, int N,
                                                      const unsigned* __restrict__ counts,
                                                      unsigned* __restrict__ cursor,
                                                      int4* __restrict__ pack) {
  __shared__ unsigned lhist[NLIST], lbase[NLIST], sbstart[NLIST];
  __shared__ unsigned wsum[16];
  const int t = threadIdx.x;
  const int base = blockIdx.x * SCHUNK;
  {
    unsigned c0 = counts[t * 2], c1 = counts[t * 2 + 1];
    unsigned sum2 = c0 + c1;
    unsigned incl = block_scan_incl(sum2, wsum, t, STHREADS / 64);
    unsigned excl = incl - sum2;
    sbstart[t * 2] = excl;
    sbstart[t * 2 + 1] = excl + c0;
  }
  for (int i = t; i < NLIST; i += STHREADS) lhist[i] = 0;
  __syncthreads();
  #pragma unroll
  for (int k = 0; k < SCHUNK / STHREADS; ++k) {
    int n = base + k * STHREADS + t;
    if (n < N) atomicAdd(&lhist[db_list[n]], 1u);
  }
  __syncthreads();
  for (int i = t; i < NLIST; i += STHREADS) {
    unsigned cnt = lhist[i];
    if (cnt) lbase[i] = sbstart[i] + atomicAdd(&cursor[i], cnt);
    lhist[i] = 0;
  }
  __syncthreads();
  #pragma unroll
  for (int k = 0; k < SCHUNK / STHREADS; ++k) {
    int n = base + k * STHREADS + t;
    if (n < N) {
      int l = db_list[n];
      unsigned pos = lbase[l] + atomicAdd(&lhist[l], 1u);
      const int4* cp = (const int4*)(db_codes + (size_t)n * MSUB);
      int4 c0 = cp[0], c1 = cp[1];
      unsigned lo = (unsigned)(c0.x & 255) | ((unsigned)(c0.y & 255) << 8) |
                    ((unsigned)(c0.z & 255) << 16) | ((unsigned)(c0.w & 255) << 24);
      unsigned hi = (unsigned)(c1.x & 255) | ((unsigned)(c1.y & 255) << 8) |
                    ((unsigned)(c1.z & 255) << 16) | ((unsigned)(c1.w & 255) << 24);
      pack[pos] = make_int4((int)lo, (int)hi, n, 0);
    }
  }
}

// ---------------- search: LUT + coarse select + ADC + top-k, 1024 thr/query ----
__global__ __launch_bounds__(1024, 1) void k_search(const float* __restrict__ queries,
                                                    const float* __restrict__ codebooks,
                                                    const unsigned long long* __restrict__ keys_g,
                                                    const unsigned* __restrict__ counts,
                                                    const int4* __restrict__ pack,
                                                    int* __restrict__ out) {
  const int qi = blockIdx.x;
  const int t = threadIdx.x;
  __shared__ float qs[DDIM];
  __shared__ float lut_s[MSUB * KCODE];
  __shared__ unsigned hist[HBINS];
  __shared__ unsigned long long coll[COLL_CAP];
  __shared__ unsigned bst[NLIST + 1];
  __shared__ unsigned pstart[NPROBE], pcum[NPROBE + 1];
  __shared__ unsigned wsum[16];
  __shared__ unsigned scnt;
  __shared__ int sT;

  if (t < DDIM) qs[t] = queries[qi * DDIM + t];
  const unsigned long long ckey = keys_g[(size_t)qi * NLIST + t];
  for (int i = t; i < HBINS; i += 1024) hist[i] = 0;
  if (t == 0) { scnt = 0; sT = HBINS - 1; }
  // bst = exclusive prefix of counts (internal syncs also cover qs/hist init)
  {
    unsigned v = counts[t];
    unsigned incl = block_scan_incl(v, wsum, t, 16);
    bst[t + 1] = incl;
    if (t == 0) bst[0] = 0;
  }
  __syncthreads();

  // ---- LUT (frozen arithmetic), 2 entries per thread; float4 codebook loads ----
  #pragma unroll
  for (int j = 0; j < (MSUB * KCODE) / 1024; ++j) {
    int idx = j * 1024 + t;
    const float* cb = codebooks + (size_t)idx * DSUB;
    const float* qsub = qs + (idx >> 8) * DSUB;  // KCODE == 256
    float cbv[DSUB], qv[DSUB];
    #pragma unroll
    for (int d = 0; d < DSUB; d += 4) {
      float4 cv = *(const float4*)(cb + d);
      cbv[d] = cv.x; cbv[d + 1] = cv.y; cbv[d + 2] = cv.z; cbv[d + 3] = cv.w;
    }
    #pragma unroll
    for (int d = 0; d < DSUB; ++d) qv[d] = qsub[d];
    const float qq16 = xla_sumsq16(qv);
    const float cc16 = xla_sumsq16(cbv);
    const float dot16 = chain_dot16(qv, cbv);
    lut_s[idx] = __fsub_rn(__fadd_rn(qq16, cc16), __fmul_rn(2.0f, dot16));
  }

  // ---- coarse top-NPROBE selection from ckey ----
  atomicAdd(&hist[(unsigned)(ckey >> 51)], 1u);
  __syncthreads();
  {
    unsigned mysum = 0;
    #pragma unroll
    for (int i = 0; i < 4; ++i) mysum += hist[t * 4 + i];
    unsigned incl = block_scan_incl(mysum, wsum, t, 16);
    unsigned excl = incl - mysum;
    if (excl < NPROBE && NPROBE <= incl) {
      unsigned c2 = excl;
      #pragma unroll
      for (int i = 0; i < 4; ++i) {
        unsigned h = hist[t * 4 + i];
        if (c2 + h >= NPROBE) { sT = t * 4 + i; break; }
        c2 += h;
      }
    }
  }
  __syncthreads();
  {
    const int T32 = sT;
    if ((int)(ckey >> 51) <= T32) {
      unsigned p = atomicAdd(&scnt, 1u);
      if (p < 512) coll[p] = ckey;
    }
  }
  __syncthreads();
  {
    unsigned cnt = scnt; if (cnt > 512) cnt = 512;
    for (unsigned i = t; i < cnt; i += 1024) {
      unsigned long long k2 = coll[i];
      unsigned r = 0;
      for (unsigned j = 0; j < cnt; ++j) r += (coll[j] < k2) ? 1u : 0u;
      if (r < NPROBE) {
        unsigned l = (unsigned)(k2 & 0xffffffffULL);
        pstart[r] = bst[l];
        pcum[r + 1] = bst[l + 1] - bst[l];
      }
    }
  }
  __syncthreads();
  // reset for ADC phase
  for (int i = t; i < HBINS; i += 1024) hist[i] = 0;
  if (t == 0) {
    scnt = 0; sT = HBINS - 1;
    unsigned acc = 0;
    pcum[0] = 0;
    for (int j = 1; j <= NPROBE; ++j) { acc += pcum[j]; pcum[j] = acc; }
  }
  __syncthreads();
  const unsigned total = pcum[NPROBE];

  // ---- pass 1: ADC once, keys in STATICALLY-indexed registers,
  //      probe lookup via monotonic walk (g strictly increases per thread) ----
  unsigned long long regkey[RCAP];
  int lo = 0;
  #pragma unroll
  for (int s = 0; s < RCAP; ++s) {
    unsigned g = (unsigned)t + (unsigned)(s * 1024);
    if (g < total) {
      while (pcum[lo + 1] <= g) ++lo;
      unsigned addr = pstart[lo] + (g - pcum[lo]);
      int4 w = pack[addr];
      unsigned long long code = (unsigned)w.x | ((unsigned long long)(unsigned)w.y << 32);
      unsigned bits = __float_as_uint(adc_dist(lut_s, code));
      regkey[s] = ((unsigned long long)bits << 32) | (unsigned)w.z;
      atomicAdd(&hist[bits >> 19], 1u);
    }
  }
  // defensive tail (never taken at this problem size: RCAP*1024 = 10240 > max total)
  for (unsigned g = (unsigned)t + RCAP * 1024; g < total; g += 1024) {
    while (pcum[lo + 1] <= g) ++lo;
    unsigned addr = pstart[lo] + (g - pcum[lo]);
    int4 w = pack[addr];
    unsigned long long code = (unsigned)w.x | ((unsigned long long)(unsigned)w.y << 32);
    unsigned bits = __float_as_uint(adc_dist(lut_s, code));
    atomicAdd(&hist[bits >> 19], 1u);
  }
  __syncthreads();

  // ---- find T = bin containing rank TOPK ----
  {
    unsigned mysum = 0;
    #pragma unroll
    for (int i = 0; i < 4; ++i) mysum += hist[t * 4 + i];
    unsigned incl = block_scan_incl(mysum, wsum, t, 16);
    unsigned excl = incl - mysum;
    if (excl < TOPK && TOPK <= incl) {
      unsigned c = excl;
      #pragma unroll
      for (int i = 0; i < 4; ++i) {
        unsigned h = hist[t * 4 + i];
        if (c + h >= TOPK) { sT = t * 4 + i; break; }
        c += h;
      }
    }
  }
  __syncthreads();
  const int T = sT;

  // ---- pass 2: collect ALL candidates with bin <= T (register replay) ----
  {
    #pragma unroll
    for (int s = 0; s < RCAP; ++s) {
      unsigned g = (unsigned)t + (unsigned)(s * 1024);
      if (g < total) {
        unsigned long long k2 = regkey[s];
        if ((int)(unsigned)(k2 >> 51) <= T) {   // == bits >> 19
          unsigned p = atomicAdd(&scnt, 1u);
          if (p < COLL_CAP) coll[p] = k2;
        }
      }
    }
    int lo2 = 0;
    for (unsigned g = (unsigned)t + RCAP * 1024; g < total; g += 1024) {
      while (pcum[lo2 + 1] <= g) ++lo2;
      unsigned addr = pstart[lo2] + (g - pcum[lo2]);
      int4 w = pack[addr];
      unsigned long long code = (unsigned)w.x | ((unsigned long long)(unsigned)w.y << 32);
      unsigned bits = __float_as_uint(adc_dist(lut_s, code));
      if ((int)(bits >> 19) <= T) {
        unsigned p = atomicAdd(&scnt, 1u);
        if (p < COLL_CAP) coll[p] = ((unsigned long long)bits << 32) | (unsigned)w.z;
      }
    }
  }
  __syncthreads();

  // ---- exact rank by (fp32 bits, index) ----
  unsigned cnt = scnt;
  if (cnt > COLL_CAP) cnt = COLL_CAP;
  for (unsigned i = t; i < cnt; i += 1024) {
    unsigned long long key = coll[i];
    unsigned r = 0;
    for (unsigned j = 0; j < cnt; ++j) r += (coll[j] < key) ? 1u : 0u;
    if (r < TOPK) out[qi * TOPK + r] = (int)(key & 0xffffffffULL);
  }
}

extern "C" void kernel_launch(void* const* d_in, const int* in_sizes, int n_in,
                              void* d_out, int out_size, void* d_ws, size_t ws_size,
                              hipStream_t stream) {
  const float* queries   = (const float*)d_in[0];
  const float* centroids = (const float*)d_in[1];
  const float* codebooks = (const float*)d_in[2];
  const int*   db_codes  = (const int*)d_in[3];
  const int*   db_list   = (const int*)d_in[4];
  const int N = in_sizes[4];
  const int Q = in_sizes[0] / DDIM;
  int* out = (int*)d_out;

  char* p = (char*)d_ws;
  unsigned long long* keys_g = (unsigned long long*)p; p += (size_t)Q * NLIST * 8;
  unsigned* counts = (unsigned*)p;                  p += NLIST * 4;
  unsigned* cursor = (unsigned*)p;                  p += NLIST * 4;
  int4* pack = (int4*)p;                            p += (size_t)N * 16;

  hipMemsetAsync(counts, 0, (size_t)NLIST * 4 * 2, stream); // counts + cursor

  k_front<<<Q * 4 + Q, 256, 0, stream>>>(queries, centroids, db_list, N, keys_g, counts);
  k_scatter<<<(N + SCHUNK - 1) / SCHUNK, STHREADS, 0, stream>>>(db_list, db_codes, N,
                                                                counts, cursor, pack);
  k_search<<<Q, 1024, 0, stream>>>(queries, codebooks, keys_g, counts, pack, out);
}